// Round 1
// baseline (240.452 us; speedup 1.0000x reference)
//
#include <hip/hip_runtime.h>

// OTAM cumulative distance, exp-space formulation.
//
// Reference DP (per problem, L=48 rows, M2=50 padded cols, lambda=0.5):
//   row0[m]   = cumsum(d[0][:])                      (col 0 and col 49 are pad=0)
//   cur[0]    = 0
//   m==1   : cur[1] = d + softmin(prev[0]=0, cur[0]=0, prev[1])
//   1<m<49 : cur[m] = d + softmin(prev[m-1], cur[m-1])
//   m==49  : cur[49] = 0 + softmin(prev[48], cur[48], prev[49])   (d pad = 0)
// answer = cum[47][49].
//
// In exp space with F[m] = exp(-cum[m]/lambda), A_m = exp(-2*d_m):
//   F[m] = A_m * (F[m-1] + P[m-1] (+ P[m] at edges, + extra 1 at m==1))
// cum in [0, ~60] -> F in [e^-120, 1]: fits f64 with fixed base, no rescaling.
// Serial chain per cell = one f64 add + one f64 mul; exps are off-chain.

__global__ __launch_bounds__(64, 1) void otam_kernel(const float* __restrict__ dists,
                                                     float* __restrict__ out) {
    const int b = blockIdx.x * 64 + threadIdx.x;  // 16384 problems
    const float* __restrict__ dp = dists + (size_t)b * (48 * 48);

    // P[i] = exp(-2 * cum[prev_row][i+1])  (cols 1..49)
    double P[49];

    // ---- Row 0: running product of A ----
    {
        const float4* __restrict__ r4 = reinterpret_cast<const float4*>(dp);
        double run = 1.0;
#pragma unroll
        for (int v = 0; v < 12; ++v) {
            float4 q = r4[v];
            run *= (double)__expf(-2.0f * q.x); P[4 * v + 0] = run;
            run *= (double)__expf(-2.0f * q.y); P[4 * v + 1] = run;
            run *= (double)__expf(-2.0f * q.z); P[4 * v + 2] = run;
            run *= (double)__expf(-2.0f * q.w); P[4 * v + 3] = run;
        }
        P[48] = run;  // col 49 is pad (A=1): cum[0][49] = cum[0][48]
    }

    // ---- Rows 1..47 ----
    for (int l = 1; l < 48; ++l) {
        const float4* __restrict__ r4 = reinterpret_cast<const float4*>(dp + l * 48);
        float a[48];
#pragma unroll
        for (int v = 0; v < 12; ++v) {
            float4 q = r4[v];
            a[4 * v + 0] = __expf(-2.0f * q.x);
            a[4 * v + 1] = __expf(-2.0f * q.y);
            a[4 * v + 2] = __expf(-2.0f * q.z);
            a[4 * v + 3] = __expf(-2.0f * q.w);
        }

        // m = 1: candidates prev[0]=0, cur[0]=0 (each contribute exp(0)=1), prev[1]
        double c = (double)a[0] * (2.0 + P[0]);  // c = F[1]

        // m = 2..48: F[m] = A_m * (F[m-1] + P[m-1]); retire F[m-1] into P[m-2]
#pragma unroll
        for (int m = 2; m <= 48; ++m) {
            double t = (double)a[m - 1] * (c + P[m - 2]);
            P[m - 2] = c;
            c = t;
        }

        // m = 49 (pad col, A=1): F[49] = F[48] + P[48] + P[49]
        double t = c + P[47] + P[48];
        P[47] = c;  // F[48]
        P[48] = t;  // F[49]
    }

    out[b] = (float)(-0.5 * log(P[48]));
}

extern "C" void kernel_launch(void* const* d_in, const int* in_sizes, int n_in,
                              void* d_out, int out_size, void* d_ws, size_t ws_size,
                              hipStream_t stream) {
    const float* dists = (const float*)d_in[0];
    float* out = (float*)d_out;
    // 16384 problems, 1 thread each; 64-thread blocks -> 256 blocks (1 per CU).
    otam_kernel<<<dim3(256), dim3(64), 0, stream>>>(dists, out);
}

// Round 2
// 216.409 us; speedup vs baseline: 1.1111x; 1.1111x over previous
//
#include <hip/hip_runtime.h>

// OTAM soft-DTW cumulative distance, exp-space + chunked affine scan.
//
// Per problem (L=48 rows, padded cols m=0..49, lambda=0.5), in exp space
// F[m] = exp(-2*cum[m]):
//   row l>=1:  F[m] = alpha_m * F[m-1] + beta_m   (affine linear recurrence)
//     alpha_m = exp(-2*d[l][m-1]) for m=1..48
//     beta_1  = alpha_1*(1 + P[1])          (edge: prev[0]=0 and cur[0]=0 both
//                                            contribute exp(0); alpha*y0 term
//                                            comes from the scan with y0=1)
//     beta_m  = alpha_m*P[m-1], 2<=m<=48
//     col 49  : F[49] = y[48] + P[48] + P[49]  (pure accumulator, lane 7)
//   row 0: beta=0 (plain cumprod of alpha).
// P[] = previous row's F.
//
// Parallelization: 8 lanes per problem, 6 columns per lane. Per row:
//   local affine compose (serial depth 6) -> 3-step Hillis-Steele scan of
//   affine maps across the 8-lane group -> 6 FMAs to apply. All f64
//   (F in [e^-120, 1], fits f64 with no rescaling). One log per problem.

__global__ __launch_bounds__(256, 2) void otam_kernel(const float* __restrict__ dists,
                                                      float* __restrict__ out) {
    const int t = blockIdx.x * 256 + threadIdx.x;
    const int k = t & 7;          // lane within 8-lane group
    const int prob = t >> 3;      // 0..16383
    const int lane = threadIdx.x & 63;

    const float* __restrict__ dp = dists + (size_t)prob * (48 * 48) + 6 * k;

    double P[6];                  // previous-row F at this lane's cols (1+6k .. 6+6k)
    double F49 = 0.0;             // col-49 accumulator (lane 7's is the real one)

    // Prefetch row 0 (24 B per lane, 8-byte aligned).
    float2 q0 = *reinterpret_cast<const float2*>(dp + 0);
    float2 q1 = *reinterpret_cast<const float2*>(dp + 2);
    float2 q2 = *reinterpret_cast<const float2*>(dp + 4);

    for (int l = 0; l < 48; ++l) {
        const float d0 = q0.x, d1 = q0.y, d2 = q1.x, d3 = q1.y, d4 = q2.x, d5 = q2.y;

        // Prefetch next row (clamp on last iter to stay in-bounds; values unused).
        {
            const float* np = dp + (l < 47 ? (l + 1) : l) * 48;
            q0 = *reinterpret_cast<const float2*>(np + 0);
            q1 = *reinterpret_cast<const float2*>(np + 2);
            q2 = *reinterpret_cast<const float2*>(np + 4);
        }

        double al[6], be[6];
        al[0] = (double)__expf(-2.0f * d0);
        al[1] = (double)__expf(-2.0f * d1);
        al[2] = (double)__expf(-2.0f * d2);
        al[3] = (double)__expf(-2.0f * d3);
        al[4] = (double)__expf(-2.0f * d4);
        al[5] = (double)__expf(-2.0f * d5);

        double Pold5 = 0.0;
        if (l == 0) {
            be[0] = 0.0; be[1] = 0.0; be[2] = 0.0; be[3] = 0.0; be[4] = 0.0; be[5] = 0.0;
        } else {
            // P[m-1] for this lane's first col lives in lane k-1 (its last col).
            double Plast = __shfl(P[5], (lane - 1) & 63);
            // Lane 0, col m=1: beta = alpha*(1 + P[1]); P[1] is this lane's own P[0].
            double pfirst = (k == 0) ? (1.0 + P[0]) : Plast;
            be[0] = al[0] * pfirst;
            be[1] = al[1] * P[0];
            be[2] = al[2] * P[1];
            be[3] = al[3] * P[2];
            be[4] = al[4] * P[3];
            be[5] = al[5] * P[4];
            Pold5 = P[5];         // F_prev[48] on lane 7, for the col-49 accumulator
        }

        // Local affine composition over this lane's 6 columns:
        // (A, B) s.t. y_end = A*y_in + B.
        double A = al[0], B = be[0];
#pragma unroll
        for (int i = 1; i < 6; ++i) {
            B = al[i] * B + be[i];
            A = al[i] * A;
        }

        // Inclusive Hillis-Steele scan of affine maps across the 8-lane group.
#pragma unroll
        for (int s = 1; s <= 4; s <<= 1) {
            double Ap = __shfl(A, (lane - s) & 63);
            double Bp = __shfl(B, (lane - s) & 63);
            // identity map for lanes that shouldn't combine
            Ap = (k >= s) ? Ap : 1.0;
            Bp = (k >= s) ? Bp : 0.0;
            B = A * Bp + B;       // cur ∘ prev
            A = A * Ap;
        }

        // y_in for this lane = inclusive map of lane k-1 applied to y0 = 1.
        double tAB = A + B;
        double yin = __shfl(tAB, (lane - 1) & 63);
        yin = (k == 0) ? 1.0 : yin;

        // Apply: materialize this lane's 6 columns, becoming the new P.
        double y = yin;
#pragma unroll
        for (int i = 0; i < 6; ++i) {
            y = al[i] * y + be[i];
            P[i] = y;
        }

        // Col 49 (lane 7): row 0: F49 = F0[48]; else F49 += y[48] + P_old[48].
        if (k == 7) {
            F49 = (l == 0) ? y : (y + Pold5 + F49);
        }
    }

    if (k == 7) {
        out[prob] = (float)(-0.5 * log(F49));
    }
}

extern "C" void kernel_launch(void* const* d_in, const int* in_sizes, int n_in,
                              void* d_out, int out_size, void* d_ws, size_t ws_size,
                              hipStream_t stream) {
    const float* dists = (const float*)d_in[0];
    float* out = (float*)d_out;
    // 16384 problems x 8 lanes = 131072 threads; 256/block -> 512 blocks.
    otam_kernel<<<dim3(512), dim3(256), 0, stream>>>(dists, out);
}

// Round 4
// 211.724 us; speedup vs baseline: 1.1357x; 1.0221x over previous
//
#include <hip/hip_runtime.h>

// OTAM soft-DTW cumulative distance, exp-space + chunked affine scan, f32.
//
// Exp space, F[m] = exp(-2*cum[m]) (lambda = 0.5):
//   row l>=1:  F[m] = alpha_m * F[m-1] + beta_m
//     alpha_m = exp(-2*d[l][m-1]),  m = 1..48
//     beta_1  = alpha_1 * (one + P[1])  (prev[0]=0 contributes exp(0)=1;
//                                        cur[0]=0 enters via scan y0=one)
//     beta_m  = alpha_m * P[m-1],  2<=m<=48
//     col 49  : F[49] = F[48] + P[48] + P[49]  (pure accumulator, lane 15)
//   row 0: plain cumprod of alpha.
// P[] = previous row's F.
//
// f32 with per-row renormalization: rescale state by 2^-E (E = exponent of
// the 16-lane group max), accumulate E in offE. CRITICAL: all state is in
// stored units (true = stored * 2^offE), so the DP's exp(0)=1 injections
// from the zero column must be injected as S = 2^-offE (stored rep of 1.0),
// NOT as literal 1.0f — this was round 3's bug (free-entry paths suppressed
// by 2^offE => +7 nat errors). S is an exact power of two (S *= sc).
// With free entry, col 1 stays cheap every row, so offE ~ ±10 and S is safe.
//
// Parallelization: 16 lanes per problem, 3 columns per lane. Per row:
// local affine partials (depth 3) -> 4-step Hillis-Steele affine scan ->
// 3 independent FMAs. 4096 waves = 4 waves/SIMD.

__global__ __launch_bounds__(256, 4) void otam_kernel(const float* __restrict__ dists,
                                                      float* __restrict__ out) {
    const int t = blockIdx.x * 256 + threadIdx.x;
    const int k = t & 15;         // lane within 16-lane group
    const int prob = t >> 4;      // 0..16383
    const int lane = threadIdx.x & 63;

    const float* __restrict__ dp = dists + (size_t)prob * (48 * 48) + 3 * k;

    float P0, P1, P2;             // previous-row F at cols 3k+1 .. 3k+3 (stored units)
    float F49 = 0.0f;             // col-49 accumulator (lane 15's is real)
    float S = 1.0f;               // stored-units rep of true 1.0 ( = 2^-offE )
    int offE = 0;                 // true = stored * 2^offE

    // Load row 0.
    float q0 = dp[0], q1 = dp[1], q2 = dp[2];

    // ---- Row 0: multiplicative scan (cumprod of alpha) ----
    {
        float a0 = __expf(-2.0f * q0);
        float a1 = __expf(-2.0f * q1);
        float a2 = __expf(-2.0f * q2);
        // prefetch row 1
        q0 = dp[48]; q1 = dp[49]; q2 = dp[50];

        float Ap0 = a0, Ap1 = a0 * a1, Ap2 = a0 * a1 * a2;
        float A = Ap2;
#pragma unroll
        for (int s = 1; s <= 8; s <<= 1) {
            float Au = __shfl(A, (lane - s) & 63);
            A *= (k >= s) ? Au : 1.0f;
        }
        float yin = __shfl(A, (lane - 1) & 63);
        yin = (k == 0) ? 1.0f : yin;   // offE == 0 here, S == 1
        P0 = Ap0 * yin; P1 = Ap1 * yin; P2 = Ap2 * yin;
        F49 = P2;  // pad col: cum[0][49] = cum[0][48]
    }

    // row-0 rescale
    {
        float m = fmaxf(P0, fmaxf(P1, P2));
#pragma unroll
        for (int s = 1; s <= 8; s <<= 1) m = fmaxf(m, __shfl_xor(m, s));
        unsigned e = (__float_as_uint(m) >> 23) & 0xFFu;
        float sc = __uint_as_float((254u - e) << 23);  // 2^(127-e)
        offE += (int)e - 127;
        P0 *= sc; P1 *= sc; P2 *= sc; F49 *= sc; S *= sc;
    }

    // ---- Rows 1..47 ----
    for (int l = 1; l < 48; ++l) {
        float a0 = __expf(-2.0f * q0);
        float a1 = __expf(-2.0f * q1);
        float a2 = __expf(-2.0f * q2);

        // prefetch next row (clamped; last-iter values unused)
        {
            const float* np = dp + (l < 47 ? (l + 1) : l) * 48;
            q0 = np[0]; q1 = np[1]; q2 = np[2];
        }

        // beta terms (all stored units)
        float Plast = __shfl(P2, (lane - 1) & 63);     // F_prev[3k] from lane k-1
        float pfirst = (k == 0) ? (S + P0) : Plast;    // edge m==1: prev[0]=0 -> S
        float be0 = a0 * pfirst;
        float be1 = a1 * P0;
        float be2 = a2 * P1;
        float PoldLast = P2;                           // F_prev[48] on lane 15

        // local affine partials: y_i = Ap_i * y_in + Bp_i
        float Ap0 = a0,        Bp0 = be0;
        float Ap1 = a1 * Ap0,  Bp1 = fmaf(a1, Bp0, be1);
        float Ap2 = a2 * Ap1,  Bp2 = fmaf(a2, Bp1, be2);

        // inclusive Hillis-Steele scan of affine maps across 16 lanes
        float A = Ap2, B = Bp2;
#pragma unroll
        for (int s = 1; s <= 8; s <<= 1) {
            float Au = __shfl(A, (lane - s) & 63);
            float Bu = __shfl(B, (lane - s) & 63);
            Au = (k >= s) ? Au : 1.0f;
            Bu = (k >= s) ? Bu : 0.0f;
            B = fmaf(A, Bu, B);
            A *= Au;
        }

        // y_in for lane k = inclusive map of lane k-1 applied to y0 = S
        // (cur[0] = 0 -> F = 1 true -> S stored)
        float incl = fmaf(A, S, B);
        float yin = __shfl(incl, (lane - 1) & 63);
        yin = (k == 0) ? S : yin;

        // apply (independent FMAs) -> new P
        P0 = fmaf(Ap0, yin, Bp0);
        P1 = fmaf(Ap1, yin, Bp1);
        P2 = fmaf(Ap2, yin, Bp2);

        // col 49 accumulator (lane 15): F49 = F[48] + P_prev[48] + F49_prev
        if (k == 15) F49 = P2 + PoldLast + F49;

        // per-row renormalization by group-max exponent
        float m = fmaxf(P0, fmaxf(P1, P2));
#pragma unroll
        for (int s = 1; s <= 8; s <<= 1) m = fmaxf(m, __shfl_xor(m, s));
        unsigned e = (__float_as_uint(m) >> 23) & 0xFFu;
        float sc = __uint_as_float((254u - e) << 23);
        offE += (int)e - 127;
        P0 *= sc; P1 *= sc; P2 *= sc; F49 *= sc; S *= sc;
    }

    if (k == 15) {
        // cum = -0.5 * ln(F49_true), F49_true = F49 * 2^offE
        out[prob] = -0.5f * (logf(F49) + (float)offE * 0.6931471805599453f);
    }
}

extern "C" void kernel_launch(void* const* d_in, const int* in_sizes, int n_in,
                              void* d_out, int out_size, void* d_ws, size_t ws_size,
                              hipStream_t stream) {
    const float* dists = (const float*)d_in[0];
    float* out = (float*)d_out;
    // 16384 problems x 16 lanes = 262144 threads; 256/block -> 1024 blocks.
    otam_kernel<<<dim3(1024), dim3(256), 0, stream>>>(dists, out);
}

// Round 5
// 210.843 us; speedup vs baseline: 1.1404x; 1.0042x over previous
//
#include <hip/hip_runtime.h>

// OTAM soft-DTW cumulative distance, exp-space chunked affine scan, f32 + DPP.
//
// Exp space, F[m] = exp(-2*cum[m]) (lambda = 0.5):
//   row l>=1:  F[m] = alpha_m * F[m-1] + beta_m
//     alpha_m = exp(-2*d[l][m-1]),  m = 1..48
//     beta_1  = alpha_1 * (S + P[1])   (prev[0]=0 -> S; cur[0]=0 enters as y0=S)
//     beta_m  = alpha_m * P[m-1]
//     col 49  : F49 = F[48] + P[48] + F49_prev   (pure accumulator, lane 11)
//   row 0: plain cumprod of alpha.
// All state in "stored units": true = stored * 2^offE; S = 2^-offE is the
// stored rep of 1.0 (exact power of two). Renorm every 4 rows by the group
// max exponent (drift over 4 rows bounded ~2^±50, safe in f32).
//
// Layout: 16 lanes per problem = one DPP row; lanes 0..11 own 4 columns each
// (cols 4k+1..4k+4), loaded as one aligned float4 per row; lanes 12-15 idle
// (compute garbage, masked out of renorm-max and output). ALL group shuffles
// are DPP row_shr (VALU pipe, ~4 cyc) — identity/S injection folded into
// DPP's `old` operand. One ds_swizzle (0x170 = bcast lane 11 within 16) per
// renorm. Prefetch one 4-row block ahead.

template<int CTRL>
__device__ __forceinline__ float dpp_mov(float src, float old) {
    return __int_as_float(__builtin_amdgcn_update_dpp(
        __float_as_int(old), __float_as_int(src), CTRL, 0xF, 0xF, false));
}

__global__ __launch_bounds__(256, 4) void otam_kernel(const float* __restrict__ dists,
                                                      float* __restrict__ out) {
    const int t = blockIdx.x * 256 + threadIdx.x;
    const int k = t & 15;     // lane within 16-lane group (DPP row)
    const int prob = t >> 4;  // 0..16383

    const float* __restrict__ base =
        dists + (size_t)prob * 2304 + ((k < 12) ? 4 * k : 0);

    float P0, P1, P2, P3;     // F_prev at cols 4k+1..4k+4 (stored units)
    float F49 = 0.0f;         // col-49 accumulator (lane 11's is real)
    float S = 1.0f;           // stored rep of true 1.0 ( = 2^-offE )
    int offE = 0;

    // rows >= 1
    auto do_row = [&](float4 q) {
        float a0 = __expf(-2.0f * q.x);
        float a1 = __expf(-2.0f * q.y);
        float a2 = __expf(-2.0f * q.z);
        float a3 = __expf(-2.0f * q.w);

        float Plast = dpp_mov<0x111>(P3, 0.0f);        // F_prev[4k] from lane k-1
        float pfirst = (k == 0) ? (S + P0) : Plast;    // edge m==1
        float be0 = a0 * pfirst;
        float be1 = a1 * P0;
        float be2 = a2 * P1;
        float be3 = a3 * P2;
        float PoldLast = P3;                           // F_prev[48] on lane 11

        float Ap0 = a0,       Bp0 = be0;
        float Ap1 = a1 * Ap0, Bp1 = fmaf(a1, Bp0, be1);
        float Ap2 = a2 * Ap1, Bp2 = fmaf(a2, Bp1, be2);
        float Ap3 = a3 * Ap2, Bp3 = fmaf(a3, Bp2, be3);

        // inclusive Hillis-Steele affine scan via DPP (identity in `old`)
        float A = Ap3, B = Bp3;
        { float Au = dpp_mov<0x111>(A, 1.0f), Bu = dpp_mov<0x111>(B, 0.0f);
          B = fmaf(A, Bu, B); A *= Au; }
        { float Au = dpp_mov<0x112>(A, 1.0f), Bu = dpp_mov<0x112>(B, 0.0f);
          B = fmaf(A, Bu, B); A *= Au; }
        { float Au = dpp_mov<0x114>(A, 1.0f), Bu = dpp_mov<0x114>(B, 0.0f);
          B = fmaf(A, Bu, B); A *= Au; }
        { float Au = dpp_mov<0x118>(A, 1.0f), Bu = dpp_mov<0x118>(B, 0.0f);
          B = fmaf(A, Bu, B); A *= Au; }

        float incl = fmaf(A, S, B);          // inclusive result applied to y0=S
        float yin = dpp_mov<0x111>(incl, S); // lane 0 gets S via `old` (no cndmask)

        P0 = fmaf(Ap0, yin, Bp0);
        P1 = fmaf(Ap1, yin, Bp1);
        P2 = fmaf(Ap2, yin, Bp2);
        P3 = fmaf(Ap3, yin, Bp3);

        F49 = P3 + PoldLast + F49;           // meaningful on lane 11 only
    };

    auto renorm = [&]() {
        float m = (k < 12) ? fmaxf(fmaxf(P0, P1), fmaxf(P2, P3)) : 0.0f;
        m = fmaxf(m, dpp_mov<0x111>(m, 0.0f));
        m = fmaxf(m, dpp_mov<0x112>(m, 0.0f));
        m = fmaxf(m, dpp_mov<0x114>(m, 0.0f));
        m = fmaxf(m, dpp_mov<0x118>(m, 0.0f));  // lane 11 = max over lanes 0..11
        // broadcast lane 11 within each 16-group: and=0x10, or=0x0B -> 0x170
        float g = __int_as_float(__builtin_amdgcn_ds_swizzle(__float_as_int(m), 0x170));
        unsigned e = (__float_as_uint(g) >> 23) & 0xFFu;
        float sc = __uint_as_float((254u - e) << 23);  // 2^(127-e)
        offE += (int)e - 127;
        P0 *= sc; P1 *= sc; P2 *= sc; P3 *= sc; F49 *= sc; S *= sc;
    };

    // load rows 0..3, then prefetch rows 4..7 before processing
    float4 c0 = *(const float4*)(base);
    float4 c1 = *(const float4*)(base + 48);
    float4 c2 = *(const float4*)(base + 96);
    float4 c3 = *(const float4*)(base + 144);
    float4 n0 = *(const float4*)(base + 192);
    float4 n1 = *(const float4*)(base + 240);
    float4 n2 = *(const float4*)(base + 288);
    float4 n3 = *(const float4*)(base + 336);

    // ---- Row 0: multiplicative scan (cumprod of alpha), offE=0, S=1 ----
    {
        float a0 = __expf(-2.0f * c0.x);
        float a1 = __expf(-2.0f * c0.y);
        float a2 = __expf(-2.0f * c0.z);
        float a3 = __expf(-2.0f * c0.w);
        float Ap0 = a0, Ap1 = Ap0 * a1, Ap2 = Ap1 * a2, Ap3 = Ap2 * a3;
        float A = Ap3;
        A *= dpp_mov<0x111>(A, 1.0f);
        A *= dpp_mov<0x112>(A, 1.0f);
        A *= dpp_mov<0x114>(A, 1.0f);
        A *= dpp_mov<0x118>(A, 1.0f);
        float yin = dpp_mov<0x111>(A, 1.0f);
        P0 = Ap0 * yin; P1 = Ap1 * yin; P2 = Ap2 * yin; P3 = Ap3 * yin;
        F49 = P3;  // pad col: cum[0][49] = cum[0][48]
    }
    do_row(c1); do_row(c2); do_row(c3);
    renorm();
    c0 = n0; c1 = n1; c2 = n2; c3 = n3;

    // ---- Blocks 1..10: process rows 4b..4b+3, prefetch rows 4b+4..4b+7 ----
    for (int b = 1; b <= 10; ++b) {
        const float* nb = base + (4 * b + 4) * 48;
        n0 = *(const float4*)(nb);
        n1 = *(const float4*)(nb + 48);
        n2 = *(const float4*)(nb + 96);
        n3 = *(const float4*)(nb + 144);
        do_row(c0); do_row(c1); do_row(c2); do_row(c3);
        renorm();
        c0 = n0; c1 = n1; c2 = n2; c3 = n3;
    }

    // ---- Tail block: rows 44..47 ----
    do_row(c0); do_row(c1); do_row(c2); do_row(c3);

    if (k == 11) {
        // cum = -0.5 * ln(F49_true), F49_true = F49 * 2^offE
        out[prob] = -0.5f * (logf(F49) + (float)offE * 0.6931471805599453f);
    }
}

extern "C" void kernel_launch(void* const* d_in, const int* in_sizes, int n_in,
                              void* d_out, int out_size, void* d_ws, size_t ws_size,
                              hipStream_t stream) {
    const float* dists = (const float*)d_in[0];
    float* out = (float*)d_out;
    // 16384 problems x 16 lanes = 262144 threads; 256/block -> 1024 blocks.
    otam_kernel<<<dim3(1024), dim3(256), 0, stream>>>(dists, out);
}

// Round 6
// 210.359 us; speedup vs baseline: 1.1431x; 1.0023x over previous
//
#include <hip/hip_runtime.h>

// OTAM soft-DTW cumulative distance, exp-space chunked affine scan, f32 + DPP,
// with 2-block-deep rotating register prefetch (A/B/C).
//
// Exp space, F[m] = exp(-2*cum[m]) (lambda = 0.5):
//   row l>=1:  F[m] = alpha_m * F[m-1] + beta_m
//     alpha_m = exp(-2*d[l][m-1]),  m = 1..48
//     beta_1  = alpha_1 * (S + P[1])   (prev[0]=0 -> S; cur[0]=0 enters as y0=S)
//     beta_m  = alpha_m * P[m-1]
//     col 49  : F49 = F[48] + P[48] + F49_prev   (accumulator, lane 11)
//   row 0: plain cumprod of alpha.
// Stored units: true = stored * 2^offE; S = 2^-offE is the stored 1.0 (exact
// power of two). Renorm every 4-row block by group-max exponent.
//
// Layout: 16 lanes/problem (one DPP row); lanes 0..11 own 4 cols each
// (cols 4k+1..4k+4) = one aligned float4 per row; lanes 12-15 idle.
// All group shuffles are DPP row_shr (identity folded into `old`); one
// ds_swizzle 0x170 (bcast lane 11 within each 16) per renorm.
//
// Pipeline: blocks of 4 rows; 3 register buffers A,B,C. Compute block b from
// its buffer, then immediately reload that buffer with block b+3 — loads have
// ~2 block-computes (x4 wave sharing) of slack before first use, and no
// buffer copies (so the compiler can use fine-grained per-buffer vmcnt).

template<int CTRL>
__device__ __forceinline__ float dpp_mov(float src, float old) {
    return __int_as_float(__builtin_amdgcn_update_dpp(
        __float_as_int(old), __float_as_int(src), CTRL, 0xF, 0xF, false));
}

__global__ __launch_bounds__(256, 4) void otam_kernel(const float* __restrict__ dists,
                                                      float* __restrict__ out) {
    const int t = blockIdx.x * 256 + threadIdx.x;
    const int k = t & 15;     // lane within 16-lane group (DPP row)
    const int prob = t >> 4;  // 0..16383

    const float* __restrict__ base =
        dists + (size_t)prob * 2304 + ((k < 12) ? 4 * k : 0);

    float P0, P1, P2, P3;     // F_prev at cols 4k+1..4k+4 (stored units)
    float F49 = 0.0f;         // col-49 accumulator (lane 11's is real)
    float S = 1.0f;           // stored rep of true 1.0 ( = 2^-offE )
    int offE = 0;

    auto do_row = [&](float4 q) {
        float a0 = __expf(-2.0f * q.x);
        float a1 = __expf(-2.0f * q.y);
        float a2 = __expf(-2.0f * q.z);
        float a3 = __expf(-2.0f * q.w);

        float Plast = dpp_mov<0x111>(P3, 0.0f);        // F_prev[4k] from lane k-1
        float pfirst = (k == 0) ? (S + P0) : Plast;    // edge m==1
        float be0 = a0 * pfirst;
        float be1 = a1 * P0;
        float be2 = a2 * P1;
        float be3 = a3 * P2;
        float PoldLast = P3;                           // F_prev[48] on lane 11

        float Ap0 = a0,       Bp0 = be0;
        float Ap1 = a1 * Ap0, Bp1 = fmaf(a1, Bp0, be1);
        float Ap2 = a2 * Ap1, Bp2 = fmaf(a2, Bp1, be2);
        float Ap3 = a3 * Ap2, Bp3 = fmaf(a3, Bp2, be3);

        // inclusive Hillis-Steele affine scan via DPP (identity in `old`)
        float A = Ap3, B = Bp3;
        { float Au = dpp_mov<0x111>(A, 1.0f), Bu = dpp_mov<0x111>(B, 0.0f);
          B = fmaf(A, Bu, B); A *= Au; }
        { float Au = dpp_mov<0x112>(A, 1.0f), Bu = dpp_mov<0x112>(B, 0.0f);
          B = fmaf(A, Bu, B); A *= Au; }
        { float Au = dpp_mov<0x114>(A, 1.0f), Bu = dpp_mov<0x114>(B, 0.0f);
          B = fmaf(A, Bu, B); A *= Au; }
        { float Au = dpp_mov<0x118>(A, 1.0f), Bu = dpp_mov<0x118>(B, 0.0f);
          B = fmaf(A, Bu, B); A *= Au; }

        float incl = fmaf(A, S, B);          // inclusive applied to y0=S
        float yin = dpp_mov<0x111>(incl, S); // lane 0 gets S via `old`

        P0 = fmaf(Ap0, yin, Bp0);
        P1 = fmaf(Ap1, yin, Bp1);
        P2 = fmaf(Ap2, yin, Bp2);
        P3 = fmaf(Ap3, yin, Bp3);

        F49 = P3 + PoldLast + F49;           // meaningful on lane 11 only
    };

    auto renorm = [&]() {
        float m = (k < 12) ? fmaxf(fmaxf(P0, P1), fmaxf(P2, P3)) : 0.0f;
        m = fmaxf(m, dpp_mov<0x111>(m, 0.0f));
        m = fmaxf(m, dpp_mov<0x112>(m, 0.0f));
        m = fmaxf(m, dpp_mov<0x114>(m, 0.0f));
        m = fmaxf(m, dpp_mov<0x118>(m, 0.0f));  // lane 11 = max over 0..11
        float g = __int_as_float(__builtin_amdgcn_ds_swizzle(__float_as_int(m), 0x170));
        unsigned e = (__float_as_uint(g) >> 23) & 0xFFu;
        float sc = __uint_as_float((254u - e) << 23);  // 2^(127-e)
        offE += (int)e - 127;
        P0 *= sc; P1 *= sc; P2 *= sc; P3 *= sc; F49 *= sc; S *= sc;
    };

    float4 A0, A1, A2, A3, B0, B1, B2, B3, C0, C1, C2, C3;

#define LOADBUF(X, blk) do {                                   \
        const float* _p = base + (blk) * 192;                  \
        X##0 = *(const float4*)(_p);                           \
        X##1 = *(const float4*)(_p + 48);                      \
        X##2 = *(const float4*)(_p + 96);                      \
        X##3 = *(const float4*)(_p + 144);                     \
    } while (0)

    LOADBUF(A, 0);
    LOADBUF(B, 1);
    LOADBUF(C, 2);

    // ---- Block 0 (buffer A): row 0 is the multiplicative scan ----
    {
        float a0 = __expf(-2.0f * A0.x);
        float a1 = __expf(-2.0f * A0.y);
        float a2 = __expf(-2.0f * A0.z);
        float a3 = __expf(-2.0f * A0.w);
        float Ap0 = a0, Ap1 = Ap0 * a1, Ap2 = Ap1 * a2, Ap3 = Ap2 * a3;
        float A = Ap3;
        A *= dpp_mov<0x111>(A, 1.0f);
        A *= dpp_mov<0x112>(A, 1.0f);
        A *= dpp_mov<0x114>(A, 1.0f);
        A *= dpp_mov<0x118>(A, 1.0f);
        float yin = dpp_mov<0x111>(A, 1.0f);
        P0 = Ap0 * yin; P1 = Ap1 * yin; P2 = Ap2 * yin; P3 = Ap3 * yin;
        F49 = P3;  // pad col: cum[0][49] = cum[0][48]
    }
    do_row(A1); do_row(A2); do_row(A3);
    renorm();
    LOADBUF(A, 3);

    // ---- Blocks 1..11, buffers rotate B,C,A,B,C,A,... ----
    // After computing block b from buffer X, reload X with block b+3.
#pragma unroll
    for (int r = 0; r < 4; ++r) {
        const int b = 3 * r;  // this iteration computes blocks b+1, b+2, b+3
        if (b + 1 < 12) {
            do_row(B0); do_row(B1); do_row(B2); do_row(B3);
            renorm();
            if (b + 4 < 12) LOADBUF(B, b + 4);
        }
        if (b + 2 < 12) {
            do_row(C0); do_row(C1); do_row(C2); do_row(C3);
            renorm();
            if (b + 5 < 12) LOADBUF(C, b + 5);
        }
        if (b + 3 < 12) {
            do_row(A0); do_row(A1); do_row(A2); do_row(A3);
            if (b + 3 < 11) renorm();  // skip the final renorm
            if (b + 6 < 12) LOADBUF(A, b + 6);
        }
    }
#undef LOADBUF

    if (k == 11) {
        // cum = -0.5 * ln(F49_true), F49_true = F49 * 2^offE
        out[prob] = -0.5f * (logf(F49) + (float)offE * 0.6931471805599453f);
    }
}

extern "C" void kernel_launch(void* const* d_in, const int* in_sizes, int n_in,
                              void* d_out, int out_size, void* d_ws, size_t ws_size,
                              hipStream_t stream) {
    const float* dists = (const float*)d_in[0];
    float* out = (float*)d_out;
    // 16384 problems x 16 lanes = 262144 threads; 256/block -> 1024 blocks.
    otam_kernel<<<dim3(1024), dim3(256), 0, stream>>>(dists, out);
}